// Round 2
// baseline (6600.153 us; speedup 1.0000x reference)
//
#include <hip/hip_runtime.h>
#include <math.h>

// Problem constants (fixed by setup_inputs)
#define NN 8192
#define NPD 128
#define F_IN 128
#define DD 512
#define HH 1024
#define EE 131072
#define NDOC 64   // 64 documents of 128 nodes each
#define NPAIR 32

// ---------------------------------------------------------------------------
// Degree / CSR construction
// ---------------------------------------------------------------------------
__global__ void k_zero_cnt(int* __restrict__ cnt) {
    int i = blockIdx.x * 256 + threadIdx.x;
    if (i < NN) cnt[i] = 0;
}

__global__ void k_count(const int* __restrict__ ei, int* __restrict__ cnt) {
    int e = blockIdx.x * 256 + threadIdx.x;
    if (e < EE) atomicAdd(&cnt[ei[EE + e]], 1);
}

__global__ void k_dinv(const int* __restrict__ cnt, float* __restrict__ dinv) {
    int i = blockIdx.x * 256 + threadIdx.x;
    if (i < NN) dinv[i] = rsqrtf((float)cnt[i] + 1.0f);
}

// exclusive scan of cnt[0..8191] -> off[0..8192], also init pos = off
__global__ void k_scan(const int* __restrict__ cnt, int* __restrict__ off,
                       int* __restrict__ pos) {
    __shared__ int part[1024];
    int t = threadIdx.x;
    int loc[8];
    int s = 0;
    int base = t * 8;
#pragma unroll
    for (int j = 0; j < 8; ++j) { loc[j] = s; s += cnt[base + j]; }
    part[t] = s;
    __syncthreads();
    for (int st = 1; st < 1024; st <<= 1) {
        int v = (t >= st) ? part[t - st] : 0;
        __syncthreads();
        part[t] += v;
        __syncthreads();
    }
    int pre = (t > 0) ? part[t - 1] : 0;
#pragma unroll
    for (int j = 0; j < 8; ++j) {
        int val = pre + loc[j];
        off[base + j] = val;
        pos[base + j] = val;
    }
    if (t == 1023) off[NN] = part[1023];
}

__global__ void k_fill(const int* __restrict__ ei, const float* __restrict__ dinv,
                       int* __restrict__ pos, int* __restrict__ csr_src,
                       float* __restrict__ csr_w) {
    int e = blockIdx.x * 256 + threadIdx.x;
    if (e >= EE) return;
    int r = ei[e];
    int c = ei[EE + e];
    int p = atomicAdd(&pos[c], 1);
    csr_src[p] = r;
    csr_w[p] = dinv[r] * dinv[c];
}

// ---------------------------------------------------------------------------
// Generic fp32 GEMM: C(n x M) = act(A(n x K) @ W(K x M) + bias)
// Tiles: 64x64 per block (256 threads, 4x4 per thread), TK=16.
// rows (n) must be multiple of 64; M arbitrary (guarded).
// ACT: 0=none, 1=relu, 2=tanh
// ---------------------------------------------------------------------------
template <int ACT>
__global__ __launch_bounds__(256) void gemm_nn(const float* __restrict__ A,
                                               const float* __restrict__ W,
                                               const float* __restrict__ bias,
                                               float* __restrict__ C, int K, int M) {
    __shared__ float As[16][68];
    __shared__ float Bs[16][68];
    const int tid = threadIdx.x;
    const int m0 = blockIdx.y * 64;
    const int n0 = blockIdx.x * 64;
    const int tx = tid & 15, ty = tid >> 4;
    const int a_m = tid >> 2, a_k = (tid & 3) << 2;
    const int b_n = tid & 63, b_k = tid >> 6;
    float acc[4][4] = {};
    const float* Arow = A + (size_t)(m0 + a_m) * K + a_k;
    const bool bok = (n0 + b_n) < M;
    const float* Bp = W + (size_t)b_k * M + n0 + b_n;

    for (int k0 = 0; k0 < K; k0 += 16) {
        float4 av = *(const float4*)(Arow + k0);
        float bv[4];
#pragma unroll
        for (int i = 0; i < 4; ++i)
            bv[i] = bok ? Bp[(size_t)(k0 + 4 * i) * M] : 0.f;
        __syncthreads();
        As[a_k + 0][a_m] = av.x;
        As[a_k + 1][a_m] = av.y;
        As[a_k + 2][a_m] = av.z;
        As[a_k + 3][a_m] = av.w;
#pragma unroll
        for (int i = 0; i < 4; ++i) Bs[b_k + 4 * i][b_n] = bv[i];
        __syncthreads();
#pragma unroll
        for (int k = 0; k < 16; ++k) {
            float4 a4 = *(const float4*)&As[k][ty * 4];
            float4 b4 = *(const float4*)&Bs[k][tx * 4];
            float ar[4] = {a4.x, a4.y, a4.z, a4.w};
            float br[4] = {b4.x, b4.y, b4.z, b4.w};
#pragma unroll
            for (int i = 0; i < 4; ++i)
#pragma unroll
                for (int j = 0; j < 4; ++j) acc[i][j] += ar[i] * br[j];
        }
    }

#pragma unroll
    for (int i = 0; i < 4; ++i) {
        int r = m0 + ty * 4 + i;
#pragma unroll
        for (int j = 0; j < 4; ++j) {
            int c = n0 + tx * 4 + j;
            if (c < M) {
                float v = acc[i][j];
                if (bias) v += bias[c];
                if (ACT == 1) v = fmaxf(v, 0.f);
                if (ACT == 2) v = tanhf(v);
                C[(size_t)r * M + c] = v;
            }
        }
    }
}

// ---------------------------------------------------------------------------
// GCN aggregation + bias + tanh:
// out[i] = tanh( sum_e w_e * xw[src_e] + dinv[i]^2 * xw[i] + b )
// one block (256 threads) per node, 2 feature dims per thread
// ---------------------------------------------------------------------------
__global__ __launch_bounds__(256) void gcn_agg(const float* __restrict__ xw,
                                               const float* __restrict__ bias,
                                               const int* __restrict__ off,
                                               const int* __restrict__ src,
                                               const float* __restrict__ wgt,
                                               const float* __restrict__ dinv,
                                               float* __restrict__ out) {
    const int node = blockIdx.x;
    const int d = threadIdx.x;
    const int beg = off[node], end = off[node + 1];
    float a0 = 0.f, a1 = 0.f;
    for (int e = beg; e < end; ++e) {
        const int s = src[e];
        const float w = wgt[e];
        const float* xs = xw + (size_t)s * DD;
        a0 += w * xs[d];
        a1 += w * xs[d + 256];
    }
    const float ns = dinv[node] * dinv[node];
    const float* xn = xw + (size_t)node * DD;
    out[(size_t)node * DD + d] = tanhf(a0 + ns * xn[d] + bias[d]);
    out[(size_t)node * DD + d + 256] = tanhf(a1 + ns * xn[d + 256] + bias[d + 256]);
}

// ---------------------------------------------------------------------------
// Attention scores: for attention-block ab (query doc ab, key doc ab^1):
// sc[ab] (128x128) = scale * Q[ab] (128x512) @ K[ab^1]^T
// grid (2,2,64), 64x64 tile per block
// ---------------------------------------------------------------------------
__global__ __launch_bounds__(256) void attn_scores(const float* __restrict__ q,
                                                   const float* __restrict__ kmat,
                                                   float* __restrict__ sc) {
    const int ab = blockIdx.z, kd = ab ^ 1;
    const float* A = q + (size_t)ab * (128 * DD);
    const float* B = kmat + (size_t)kd * (128 * DD);
    float* C = sc + (size_t)ab * (128 * 128);
    __shared__ float As[16][68];
    __shared__ float Bs[16][68];
    const int tid = threadIdx.x;
    const int m0 = blockIdx.y * 64, n0 = blockIdx.x * 64;
    const int tx = tid & 15, ty = tid >> 4;
    const int r = tid >> 2, kq = (tid & 3) << 2;
    float acc[4][4] = {};
    const float* Ap = A + (size_t)(m0 + r) * DD + kq;
    const float* Bp = B + (size_t)(n0 + r) * DD + kq;
    for (int k0 = 0; k0 < DD; k0 += 16) {
        float4 av = *(const float4*)(Ap + k0);
        float4 bv = *(const float4*)(Bp + k0);
        __syncthreads();
        As[kq + 0][r] = av.x; As[kq + 1][r] = av.y;
        As[kq + 2][r] = av.z; As[kq + 3][r] = av.w;
        Bs[kq + 0][r] = bv.x; Bs[kq + 1][r] = bv.y;
        Bs[kq + 2][r] = bv.z; Bs[kq + 3][r] = bv.w;
        __syncthreads();
#pragma unroll
        for (int k = 0; k < 16; ++k) {
            float4 a4 = *(const float4*)&As[k][ty * 4];
            float4 b4 = *(const float4*)&Bs[k][tx * 4];
            float ar[4] = {a4.x, a4.y, a4.z, a4.w};
            float br[4] = {b4.x, b4.y, b4.z, b4.w};
#pragma unroll
            for (int i = 0; i < 4; ++i)
#pragma unroll
                for (int j = 0; j < 4; ++j) acc[i][j] += ar[i] * br[j];
        }
    }
    const float scale = 0.044194173824159216f;  // 1/sqrt(512)
#pragma unroll
    for (int i = 0; i < 4; ++i)
#pragma unroll
        for (int j = 0; j < 4; ++j)
            C[(size_t)(m0 + ty * 4 + i) * 128 + n0 + tx * 4 + j] = acc[i][j] * scale;
}

// softmax over rows of 128; one wave per row
__global__ __launch_bounds__(64) void softmax128(float* __restrict__ sc) {
    const int row = blockIdx.x;
    float* p = sc + (size_t)row * 128;
    const int l = threadIdx.x;
    float a = p[l], b = p[l + 64];
    float m = fmaxf(a, b);
#pragma unroll
    for (int s = 32; s; s >>= 1) m = fmaxf(m, __shfl_xor(m, s));
    float e0 = expf(a - m), e1 = expf(b - m);
    float sum = e0 + e1;
#pragma unroll
    for (int s = 32; s; s >>= 1) sum += __shfl_xor(sum, s);
    float inv = 1.f / sum;
    p[l] = e0 * inv;
    p[l + 64] = e1 * inv;
}

// O[ab] (128x512) = P[ab] (128x128) @ V[ab^1] (128x512); grid (8,2,64)
__global__ __launch_bounds__(256) void attn_av(const float* __restrict__ sc,
                                               const float* __restrict__ v,
                                               float* __restrict__ o) {
    const int ab = blockIdx.z, kd = ab ^ 1;
    const float* A = sc + (size_t)ab * (128 * 128);
    const float* W = v + (size_t)kd * (128 * DD);
    float* C = o + (size_t)ab * (128 * DD);
    __shared__ float As[16][68];
    __shared__ float Bs[16][68];
    const int tid = threadIdx.x;
    const int m0 = blockIdx.y * 64, n0 = blockIdx.x * 64;
    const int tx = tid & 15, ty = tid >> 4;
    const int a_m = tid >> 2, a_k = (tid & 3) << 2;
    const int b_n = tid & 63, b_k = tid >> 6;
    float acc[4][4] = {};
    const float* Ap = A + (size_t)(m0 + a_m) * 128 + a_k;
    const float* Bp = W + (size_t)b_k * DD + n0 + b_n;
    for (int k0 = 0; k0 < 128; k0 += 16) {
        float4 av = *(const float4*)(Ap + k0);
        float bv[4];
#pragma unroll
        for (int i = 0; i < 4; ++i) bv[i] = Bp[(size_t)(k0 + 4 * i) * DD];
        __syncthreads();
        As[a_k + 0][a_m] = av.x; As[a_k + 1][a_m] = av.y;
        As[a_k + 2][a_m] = av.z; As[a_k + 3][a_m] = av.w;
#pragma unroll
        for (int i = 0; i < 4; ++i) Bs[b_k + 4 * i][b_n] = bv[i];
        __syncthreads();
#pragma unroll
        for (int k = 0; k < 16; ++k) {
            float4 a4 = *(const float4*)&As[k][ty * 4];
            float4 b4 = *(const float4*)&Bs[k][tx * 4];
            float ar[4] = {a4.x, a4.y, a4.z, a4.w};
            float br[4] = {b4.x, b4.y, b4.z, b4.w};
#pragma unroll
            for (int i = 0; i < 4; ++i)
#pragma unroll
                for (int j = 0; j < 4; ++j) acc[i][j] += ar[i] * br[j];
        }
    }
#pragma unroll
    for (int i = 0; i < 4; ++i)
#pragma unroll
        for (int j = 0; j < 4; ++j)
            C[(size_t)(m0 + ty * 4 + i) * DD + n0 + tx * 4 + j] = acc[i][j];
}

// ---------------------------------------------------------------------------
// fc3 (32->1) + per-doc mean pool; one block of 128 threads per doc
// ---------------------------------------------------------------------------
__global__ __launch_bounds__(128) void pool_fc3(const float* __restrict__ h32,
                                                const float* __restrict__ w3,
                                                const float* __restrict__ b3,
                                                float* __restrict__ util) {
    const int doc = blockIdx.x;
    const int t = threadIdx.x;
    const float* hp = h32 + (size_t)(doc * 128 + t) * 32;
    float s = 0.f;
#pragma unroll
    for (int j = 0; j < 32; ++j) s += hp[j] * w3[j];
    s += b3[0];
    __shared__ float red[128];
    red[t] = s;
    __syncthreads();
    for (int k = 64; k > 0; k >>= 1) {
        if (t < k) red[t] += red[t + k];
        __syncthreads();
    }
    if (t == 0) util[doc] = red[0] * (1.0f / 128.0f);
}

__global__ void final_out(const float* __restrict__ util, const int* __restrict__ ia,
                          const int* __restrict__ ib, float* __restrict__ out) {
    int i = threadIdx.x;
    if (i < NPAIR) {
        float z = util[ib[i]] - util[ia[i]];
        out[i] = 1.f / (1.f + expf(-z));
    }
}

// ---------------------------------------------------------------------------
extern "C" void kernel_launch(void* const* d_in, const int* in_sizes, int n_in,
                              void* d_out, int out_size, void* d_ws, size_t ws_size,
                              hipStream_t stream) {
    const float* x = (const float*)d_in[0];
    const float* w_in = (const float*)d_in[1];
    const float* b_in = (const float*)d_in[2];
    const float* w_mid = (const float*)d_in[3];
    const float* b_mid = (const float*)d_in[4];
    const float* w_out = (const float*)d_in[5];
    const float* b_out = (const float*)d_in[6];
    const float* fc1_w = (const float*)d_in[7];
    const float* fc1_b = (const float*)d_in[8];
    const float* fc2_w = (const float*)d_in[9];
    const float* fc2_b = (const float*)d_in[10];
    const float* fc3_w = (const float*)d_in[11];
    const float* fc3_b = (const float*)d_in[12];
    const float* qkv1_w = (const float*)d_in[13];
    const float* qkv1_b = (const float*)d_in[14];
    const float* qkv2_w = (const float*)d_in[15];
    const float* qkv2_b = (const float*)d_in[16];
    const float* qkv3_w = (const float*)d_in[17];
    const float* qkv3_b = (const float*)d_in[18];
    const int* ei = (const int*)d_in[19];
    const int* idx_a = (const int*)d_in[22];
    const int* idx_b = (const int*)d_in[23];
    float* out = (float*)d_out;

    char* ws = (char*)d_ws;
    const size_t MB = 1024 * 1024;
    float* dinv = (float*)(ws + 0);
    int* cnt = (int*)(ws + (64 << 10));
    int* off = (int*)(ws + (128 << 10));
    int* pos = (int*)(ws + (192 << 10));
    int* csrc = (int*)(ws + (256 << 10));
    float* cw = (float*)(ws + (768 << 10));
    float* util = (float*)(ws + (1280 << 10));
    // Region A (32MB): h | xw; t1 aliases the whole region (dead by then)
    float* h = (float*)(ws + 2 * MB);    // 16MB
    float* xw = (float*)(ws + 18 * MB);  // 16MB
    float* t1 = h;                       // 32MB alias, live only inside qkv MLP
    float* g = (float*)(ws + 34 * MB);   // 16MB
    // Region B (32MB): t2; sc + h32 alias it (live only after t2 dead)
    float* t2 = (float*)(ws + 50 * MB);   // 32MB
    float* sc = t2;                       // 4MB alias
    float* h32 = (float*)(ws + 58 * MB);  // 1MB alias
    float* q = (float*)(ws + 82 * MB);    // 16MB
    float* kb = (float*)(ws + 98 * MB);   // 16MB
    float* vb = (float*)(ws + 114 * MB);  // 16MB  (total 130MB)

    // --- degree + CSR build ---
    k_zero_cnt<<<NN / 256, 256, 0, stream>>>(cnt);
    k_count<<<EE / 256, 256, 0, stream>>>(ei, cnt);
    k_dinv<<<NN / 256, 256, 0, stream>>>(cnt, dinv);
    k_scan<<<1, 1024, 0, stream>>>(cnt, off, pos);
    k_fill<<<EE / 256, 256, 0, stream>>>(ei, dinv, pos, csrc, cw);

    auto layer = [&](const float* hin, const float* w, const float* b, int Kin) {
        // GCN
        gemm_nn<0><<<dim3(DD / 64, NN / 64), 256, 0, stream>>>(hin, w, nullptr, xw, Kin, DD);
        gcn_agg<<<NN, 256, 0, stream>>>(xw, b, off, csrc, cw, dinv, g);
        // qkv MLPs (t = 0:q, 1:k, 2:v)
        float* dst[3] = {q, kb, vb};
        for (int t = 0; t < 3; ++t) {
            gemm_nn<1><<<dim3(HH / 64, NN / 64), 256, 0, stream>>>(
                g, qkv1_w + (size_t)t * DD * HH, qkv1_b + (size_t)t * HH, t1, DD, HH);
            gemm_nn<1><<<dim3(HH / 64, NN / 64), 256, 0, stream>>>(
                t1, qkv2_w + (size_t)t * HH * HH, qkv2_b + (size_t)t * HH, t2, HH, HH);
            gemm_nn<1><<<dim3(DD / 64, NN / 64), 256, 0, stream>>>(
                t2, qkv3_w + (size_t)t * HH * DD, qkv3_b + (size_t)t * DD, dst[t], HH, DD);
        }
        // cross-document attention (64 independent 128x128 blocks)
        attn_scores<<<dim3(2, 2, NDOC), 256, 0, stream>>>(q, kb, sc);
        softmax128<<<NDOC * 128, 64, 0, stream>>>(sc);
        attn_av<<<dim3(8, 2, NDOC), 256, 0, stream>>>(sc, vb, h);
    };

    layer(x, w_in, b_in, F_IN);
    layer(h, w_mid, b_mid, DD);
    layer(h, w_mid, b_mid, DD);
    layer(h, w_out, b_out, DD);

    // final FCs + pool + pairwise sigmoid
    gemm_nn<2><<<dim3(DD / 64, NN / 64), 256, 0, stream>>>(h, fc1_w, fc1_b, xw, DD, DD);
    gemm_nn<2><<<dim3(1, NN / 64), 256, 0, stream>>>(xw, fc2_w, fc2_b, h32, DD, 32);
    pool_fc3<<<NDOC, 128, 0, stream>>>(h32, fc3_w, fc3_b, util);
    final_out<<<1, 64, 0, stream>>>(util, idx_a, idx_b, out);
}

// Round 3
// 1538.511 us; speedup vs baseline: 4.2900x; 4.2900x over previous
//
#include <hip/hip_runtime.h>
#include <math.h>

// Problem constants (fixed by setup_inputs)
#define NN 8192
#define NPD 128
#define F_IN 128
#define DD 512
#define HH 1024
#define EE 131072
#define NDOC 64
#define NPAIR 32

typedef __attribute__((ext_vector_type(8))) short bf16x8;
typedef __attribute__((ext_vector_type(4))) float f32x4;
typedef const __attribute__((address_space(1))) void* gas_ptr;
typedef __attribute__((address_space(3))) void* las_ptr;

__device__ __forceinline__ unsigned short f2b(float f) {
    union { float f; unsigned u; } v; v.f = f;
    unsigned r = v.u + 0x7fffu + ((v.u >> 16) & 1u);
    return (unsigned short)(r >> 16);
}

// ---------------------------------------------------------------------------
// Degree / CSR construction
// ---------------------------------------------------------------------------
__global__ void k_zero_cnt(int* __restrict__ cnt) {
    int i = blockIdx.x * 256 + threadIdx.x;
    if (i < NN) cnt[i] = 0;
}

__global__ void k_count(const int* __restrict__ ei, int* __restrict__ cnt) {
    int e = blockIdx.x * 256 + threadIdx.x;
    if (e < EE) atomicAdd(&cnt[ei[EE + e]], 1);
}

__global__ void k_dinv(const int* __restrict__ cnt, float* __restrict__ dinv) {
    int i = blockIdx.x * 256 + threadIdx.x;
    if (i < NN) dinv[i] = rsqrtf((float)cnt[i] + 1.0f);
}

__global__ void k_scan(const int* __restrict__ cnt, int* __restrict__ off,
                       int* __restrict__ pos) {
    __shared__ int part[1024];
    int t = threadIdx.x;
    int loc[8];
    int s = 0;
    int base = t * 8;
#pragma unroll
    for (int j = 0; j < 8; ++j) { loc[j] = s; s += cnt[base + j]; }
    part[t] = s;
    __syncthreads();
    for (int st = 1; st < 1024; st <<= 1) {
        int v = (t >= st) ? part[t - st] : 0;
        __syncthreads();
        part[t] += v;
        __syncthreads();
    }
    int pre = (t > 0) ? part[t - 1] : 0;
#pragma unroll
    for (int j = 0; j < 8; ++j) {
        int val = pre + loc[j];
        off[base + j] = val;
        pos[base + j] = val;
    }
    if (t == 1023) off[NN] = part[1023];
}

__global__ void k_fill(const int* __restrict__ ei, const float* __restrict__ dinv,
                       int* __restrict__ pos, int* __restrict__ csr_src,
                       float* __restrict__ csr_w) {
    int e = blockIdx.x * 256 + threadIdx.x;
    if (e >= EE) return;
    int r = ei[e];
    int c = ei[EE + e];
    int p = atomicAdd(&pos[c], 1);
    csr_src[p] = r;
    csr_w[p] = dinv[r] * dinv[c];
}

// ---------------------------------------------------------------------------
// fp32 -> bf16 cast (x input)
// ---------------------------------------------------------------------------
__global__ void k_cast(const float* __restrict__ in, unsigned short* __restrict__ out,
                       int n) {
    int i = (blockIdx.x * 256 + threadIdx.x) * 4;
    if (i < n) {
        float4 v = *(const float4*)(in + i);
        out[i + 0] = f2b(v.x);
        out[i + 1] = f2b(v.y);
        out[i + 2] = f2b(v.z);
        out[i + 3] = f2b(v.w);
    }
}

// transpose W (K x M fp32) -> Wt (M x K bf16). grid (M/32, K/32), block (32,8)
__global__ void k_tr(const float* __restrict__ in, unsigned short* __restrict__ out,
                     int K, int M) {
    __shared__ float t[32][33];
    int bx = blockIdx.x * 32;  // M
    int by = blockIdx.y * 32;  // K
    int tx = threadIdx.x, ty = threadIdx.y;
    for (int i = ty; i < 32; i += 8)
        t[i][tx] = in[(size_t)(by + i) * M + bx + tx];
    __syncthreads();
    for (int i = ty; i < 32; i += 8)
        out[(size_t)(bx + i) * K + by + tx] = f2b(t[tx][i]);
}

// ---------------------------------------------------------------------------
// bf16 MFMA GEMM: C(n x M) = act(A(n x K) @ W + bias), W given as Wt (M x K bf16)
// 128x128 tile, 256 threads (4 waves, 2x2), BK=64, global_load_lds staging.
// ACT: 0=none 1=relu 2=tanh; OUTB: 1 -> bf16 out, 0 -> fp32 out.
// Requires: n % 128 == 0, M % 128 == 0, K % 64 == 0.
// ---------------------------------------------------------------------------
template <int ACT, int OUTB>
__global__ __launch_bounds__(256) void gemm_mfma(const unsigned short* __restrict__ A,
                                                 const unsigned short* __restrict__ Bt,
                                                 const float* __restrict__ bias,
                                                 void* __restrict__ Cout, int K, int M) {
    __shared__ unsigned short As[128 * 64];
    __shared__ unsigned short Bs[128 * 64];
    const int tid = threadIdx.x;
    const int wave = tid >> 6, lane = tid & 63;
    const int m0 = blockIdx.y * 128;  // output rows (N dim)
    const int n0 = blockIdx.x * 128;  // output cols (M dim)
    const int wm = (wave & 1) * 64, wn = (wave >> 1) * 64;
    const int lhi = lane >> 4;   // quad 0..3
    const int llo = lane & 15;
    f32x4 acc[4][4] = {};

    // staging: instruction r of wave w loads 8 rows starting at w*32 + r*8;
    // lane i -> row (i>>3), 16B segment (i&7). LDS base wave-uniform (G-load-lds).
    const int srow = lane >> 3;
    const int scol = (lane & 7) * 8;
    const unsigned short* ag = A + (size_t)(m0 + wave * 32 + srow) * K + scol;
    const unsigned short* bg = Bt + (size_t)(n0 + wave * 32 + srow) * K + scol;
    unsigned short* al = As + wave * 2048;
    unsigned short* bl = Bs + wave * 2048;

    for (int k0 = 0; k0 < K; k0 += 64) {
#pragma unroll
        for (int r = 0; r < 4; ++r) {
            __builtin_amdgcn_global_load_lds((gas_ptr)(ag + k0 + (size_t)r * 8 * K),
                                             (las_ptr)(al + r * 512), 16, 0, 0);
            __builtin_amdgcn_global_load_lds((gas_ptr)(bg + k0 + (size_t)r * 8 * K),
                                             (las_ptr)(bl + r * 512), 16, 0, 0);
        }
        __syncthreads();   // drains vmcnt then barrier: LDS tile ready
#pragma unroll
        for (int s = 0; s < 2; ++s) {
            bf16x8 af[4], bf[4];
#pragma unroll
            for (int i = 0; i < 4; ++i) {
                af[i] = *(const bf16x8*)(As + (wm + i * 16 + llo) * 64 + s * 32 + lhi * 8);
                bf[i] = *(const bf16x8*)(Bs + (wn + i * 16 + llo) * 64 + s * 32 + lhi * 8);
            }
#pragma unroll
            for (int i = 0; i < 4; ++i)
#pragma unroll
                for (int j = 0; j < 4; ++j)
                    acc[i][j] = __builtin_amdgcn_mfma_f32_16x16x32_bf16(af[i], bf[j],
                                                                        acc[i][j], 0, 0, 0);
        }
        __syncthreads();   // all waves done reading before next overwrite
    }

#pragma unroll
    for (int j = 0; j < 4; ++j) {
        const int col = n0 + wn + j * 16 + llo;
        const float bv = bias ? bias[col] : 0.f;
#pragma unroll
        for (int i = 0; i < 4; ++i) {
            const size_t rbase = (size_t)(m0 + wm + i * 16 + lhi * 4) * M + col;
#pragma unroll
            for (int r = 0; r < 4; ++r) {
                float v = acc[i][j][r] + bv;
                if (ACT == 1) v = fmaxf(v, 0.f);
                if (ACT == 2) v = tanhf(v);
                if (OUTB)
                    ((unsigned short*)Cout)[rbase + (size_t)r * M] = f2b(v);
                else
                    ((float*)Cout)[rbase + (size_t)r * M] = v;
            }
        }
    }
}

// ---------------------------------------------------------------------------
// fp32 GEMM (kept for fc2, M=32): C = tanh(A@W + b)
// ---------------------------------------------------------------------------
template <int ACT>
__global__ __launch_bounds__(256) void gemm_nn(const float* __restrict__ A,
                                               const float* __restrict__ W,
                                               const float* __restrict__ bias,
                                               float* __restrict__ C, int K, int M) {
    __shared__ float As[16][68];
    __shared__ float Bs[16][68];
    const int tid = threadIdx.x;
    const int m0 = blockIdx.y * 64;
    const int n0 = blockIdx.x * 64;
    const int tx = tid & 15, ty = tid >> 4;
    const int a_m = tid >> 2, a_k = (tid & 3) << 2;
    const int b_n = tid & 63, b_k = tid >> 6;
    float acc[4][4] = {};
    const float* Arow = A + (size_t)(m0 + a_m) * K + a_k;
    const bool bok = (n0 + b_n) < M;
    const float* Bp = W + (size_t)b_k * M + n0 + b_n;

    for (int k0 = 0; k0 < K; k0 += 16) {
        float4 av = *(const float4*)(Arow + k0);
        float bv[4];
#pragma unroll
        for (int i = 0; i < 4; ++i)
            bv[i] = bok ? Bp[(size_t)(k0 + 4 * i) * M] : 0.f;
        __syncthreads();
        As[a_k + 0][a_m] = av.x;
        As[a_k + 1][a_m] = av.y;
        As[a_k + 2][a_m] = av.z;
        As[a_k + 3][a_m] = av.w;
#pragma unroll
        for (int i = 0; i < 4; ++i) Bs[b_k + 4 * i][b_n] = bv[i];
        __syncthreads();
#pragma unroll
        for (int k = 0; k < 16; ++k) {
            float4 a4 = *(const float4*)&As[k][ty * 4];
            float4 b4 = *(const float4*)&Bs[k][tx * 4];
            float ar[4] = {a4.x, a4.y, a4.z, a4.w};
            float br[4] = {b4.x, b4.y, b4.z, b4.w};
#pragma unroll
            for (int i = 0; i < 4; ++i)
#pragma unroll
                for (int j = 0; j < 4; ++j) acc[i][j] += ar[i] * br[j];
        }
    }

#pragma unroll
    for (int i = 0; i < 4; ++i) {
        int r = m0 + ty * 4 + i;
#pragma unroll
        for (int j = 0; j < 4; ++j) {
            int c = n0 + tx * 4 + j;
            if (c < M) {
                float v = acc[i][j];
                if (bias) v += bias[c];
                if (ACT == 1) v = fmaxf(v, 0.f);
                if (ACT == 2) v = tanhf(v);
                C[(size_t)r * M + c] = v;
            }
        }
    }
}

// ---------------------------------------------------------------------------
// GCN aggregation + bias + tanh, bf16 output
// ---------------------------------------------------------------------------
__global__ __launch_bounds__(256) void gcn_agg(const float* __restrict__ xw,
                                               const float* __restrict__ bias,
                                               const int* __restrict__ off,
                                               const int* __restrict__ src,
                                               const float* __restrict__ wgt,
                                               const float* __restrict__ dinv,
                                               unsigned short* __restrict__ out) {
    const int node = blockIdx.x;
    const int d = threadIdx.x;
    const int beg = off[node], end = off[node + 1];
    float a0 = 0.f, a1 = 0.f;
    for (int e = beg; e < end; ++e) {
        const int s = src[e];
        const float w = wgt[e];
        const float* xs = xw + (size_t)s * DD;
        a0 += w * xs[d];
        a1 += w * xs[d + 256];
    }
    const float ns = dinv[node] * dinv[node];
    const float* xn = xw + (size_t)node * DD;
    out[(size_t)node * DD + d] = f2b(tanhf(a0 + ns * xn[d] + bias[d]));
    out[(size_t)node * DD + d + 256] = f2b(tanhf(a1 + ns * xn[d + 256] + bias[d + 256]));
}

// ---------------------------------------------------------------------------
// Attention (fp32): scores, softmax, AV (AV writes bf16)
// ---------------------------------------------------------------------------
__global__ __launch_bounds__(256) void attn_scores(const float* __restrict__ q,
                                                   const float* __restrict__ kmat,
                                                   float* __restrict__ sc) {
    const int ab = blockIdx.z, kd = ab ^ 1;
    const float* A = q + (size_t)ab * (128 * DD);
    const float* B = kmat + (size_t)kd * (128 * DD);
    float* C = sc + (size_t)ab * (128 * 128);
    __shared__ float As[16][68];
    __shared__ float Bs[16][68];
    const int tid = threadIdx.x;
    const int m0 = blockIdx.y * 64, n0 = blockIdx.x * 64;
    const int tx = tid & 15, ty = tid >> 4;
    const int r = tid >> 2, kq = (tid & 3) << 2;
    float acc[4][4] = {};
    const float* Ap = A + (size_t)(m0 + r) * DD + kq;
    const float* Bp = B + (size_t)(n0 + r) * DD + kq;
    for (int k0 = 0; k0 < DD; k0 += 16) {
        float4 av = *(const float4*)(Ap + k0);
        float4 bv = *(const float4*)(Bp + k0);
        __syncthreads();
        As[kq + 0][r] = av.x; As[kq + 1][r] = av.y;
        As[kq + 2][r] = av.z; As[kq + 3][r] = av.w;
        Bs[kq + 0][r] = bv.x; Bs[kq + 1][r] = bv.y;
        Bs[kq + 2][r] = bv.z; Bs[kq + 3][r] = bv.w;
        __syncthreads();
#pragma unroll
        for (int k = 0; k < 16; ++k) {
            float4 a4 = *(const float4*)&As[k][ty * 4];
            float4 b4 = *(const float4*)&Bs[k][tx * 4];
            float ar[4] = {a4.x, a4.y, a4.z, a4.w};
            float br[4] = {b4.x, b4.y, b4.z, b4.w};
#pragma unroll
            for (int i = 0; i < 4; ++i)
#pragma unroll
                for (int j = 0; j < 4; ++j) acc[i][j] += ar[i] * br[j];
        }
    }
    const float scale = 0.044194173824159216f;  // 1/sqrt(512)
#pragma unroll
    for (int i = 0; i < 4; ++i)
#pragma unroll
        for (int j = 0; j < 4; ++j)
            C[(size_t)(m0 + ty * 4 + i) * 128 + n0 + tx * 4 + j] = acc[i][j] * scale;
}

__global__ __launch_bounds__(64) void softmax128(float* __restrict__ sc) {
    const int row = blockIdx.x;
    float* p = sc + (size_t)row * 128;
    const int l = threadIdx.x;
    float a = p[l], b = p[l + 64];
    float m = fmaxf(a, b);
#pragma unroll
    for (int s = 32; s; s >>= 1) m = fmaxf(m, __shfl_xor(m, s));
    float e0 = expf(a - m), e1 = expf(b - m);
    float sum = e0 + e1;
#pragma unroll
    for (int s = 32; s; s >>= 1) sum += __shfl_xor(sum, s);
    float inv = 1.f / sum;
    p[l] = e0 * inv;
    p[l + 64] = e1 * inv;
}

__global__ __launch_bounds__(256) void attn_av(const float* __restrict__ sc,
                                               const float* __restrict__ v,
                                               unsigned short* __restrict__ o) {
    const int ab = blockIdx.z, kd = ab ^ 1;
    const float* A = sc + (size_t)ab * (128 * 128);
    const float* W = v + (size_t)kd * (128 * DD);
    unsigned short* C = o + (size_t)ab * (128 * DD);
    __shared__ float As[16][68];
    __shared__ float Bs[16][68];
    const int tid = threadIdx.x;
    const int m0 = blockIdx.y * 64, n0 = blockIdx.x * 64;
    const int tx = tid & 15, ty = tid >> 4;
    const int a_m = tid >> 2, a_k = (tid & 3) << 2;
    const int b_n = tid & 63, b_k = tid >> 6;
    float acc[4][4] = {};
    const float* Ap = A + (size_t)(m0 + a_m) * 128 + a_k;
    const float* Bp = W + (size_t)b_k * DD + n0 + b_n;
    for (int k0 = 0; k0 < 128; k0 += 16) {
        float4 av = *(const float4*)(Ap + k0);
        float bv[4];
#pragma unroll
        for (int i = 0; i < 4; ++i) bv[i] = Bp[(size_t)(k0 + 4 * i) * DD];
        __syncthreads();
        As[a_k + 0][a_m] = av.x; As[a_k + 1][a_m] = av.y;
        As[a_k + 2][a_m] = av.z; As[a_k + 3][a_m] = av.w;
#pragma unroll
        for (int i = 0; i < 4; ++i) Bs[b_k + 4 * i][b_n] = bv[i];
        __syncthreads();
#pragma unroll
        for (int k = 0; k < 16; ++k) {
            float4 a4 = *(const float4*)&As[k][ty * 4];
            float4 b4 = *(const float4*)&Bs[k][tx * 4];
            float ar[4] = {a4.x, a4.y, a4.z, a4.w};
            float br[4] = {b4.x, b4.y, b4.z, b4.w};
#pragma unroll
            for (int i = 0; i < 4; ++i)
#pragma unroll
                for (int j = 0; j < 4; ++j) acc[i][j] += ar[i] * br[j];
        }
    }
#pragma unroll
    for (int i = 0; i < 4; ++i)
#pragma unroll
        for (int j = 0; j < 4; ++j)
            C[(size_t)(m0 + ty * 4 + i) * DD + n0 + tx * 4 + j] = f2b(acc[i][j]);
}

// ---------------------------------------------------------------------------
__global__ __launch_bounds__(128) void pool_fc3(const float* __restrict__ h32,
                                                const float* __restrict__ w3,
                                                const float* __restrict__ b3,
                                                float* __restrict__ util) {
    const int doc = blockIdx.x;
    const int t = threadIdx.x;
    const float* hp = h32 + (size_t)(doc * 128 + t) * 32;
    float s = 0.f;
#pragma unroll
    for (int j = 0; j < 32; ++j) s += hp[j] * w3[j];
    s += b3[0];
    __shared__ float red[128];
    red[t] = s;
    __syncthreads();
    for (int k = 64; k > 0; k >>= 1) {
        if (t < k) red[t] += red[t + k];
        __syncthreads();
    }
    if (t == 0) util[doc] = red[0] * (1.0f / 128.0f);
}

__global__ void final_out(const float* __restrict__ util, const int* __restrict__ ia,
                          const int* __restrict__ ib, float* __restrict__ out) {
    int i = threadIdx.x;
    if (i < NPAIR) {
        float z = util[ib[i]] - util[ia[i]];
        out[i] = 1.f / (1.f + expf(-z));
    }
}

// ---------------------------------------------------------------------------
extern "C" void kernel_launch(void* const* d_in, const int* in_sizes, int n_in,
                              void* d_out, int out_size, void* d_ws, size_t ws_size,
                              hipStream_t stream) {
    const float* x = (const float*)d_in[0];
    const float* w_in = (const float*)d_in[1];
    const float* b_in = (const float*)d_in[2];
    const float* w_mid = (const float*)d_in[3];
    const float* b_mid = (const float*)d_in[4];
    const float* w_out = (const float*)d_in[5];
    const float* b_out = (const float*)d_in[6];
    const float* fc1_w = (const float*)d_in[7];
    const float* fc1_b = (const float*)d_in[8];
    const float* fc2_w = (const float*)d_in[9];
    const float* fc2_b = (const float*)d_in[10];
    const float* fc3_w = (const float*)d_in[11];
    const float* fc3_b = (const float*)d_in[12];
    const float* qkv1_w = (const float*)d_in[13];
    const float* qkv1_b = (const float*)d_in[14];
    const float* qkv2_w = (const float*)d_in[15];
    const float* qkv2_b = (const float*)d_in[16];
    const float* qkv3_w = (const float*)d_in[17];
    const float* qkv3_b = (const float*)d_in[18];
    const int* ei = (const int*)d_in[19];
    const int* idx_a = (const int*)d_in[22];
    const int* idx_b = (const int*)d_in[23];
    float* out = (float*)d_out;

    char* ws = (char*)d_ws;
    const size_t MB = 1024 * 1024;
    const size_t KB = 1024;
    float* dinv = (float*)(ws + 0);
    int* cnt = (int*)(ws + 64 * KB);
    int* off = (int*)(ws + 128 * KB);
    int* pos = (int*)(ws + 192 * KB);
    int* csrc = (int*)(ws + 256 * KB);
    float* cw = (float*)(ws + 768 * KB);
    float* util = (float*)(ws + 1280 * KB);
    unsigned short* xb = (unsigned short*)(ws + 2 * MB);        // 2MB (8192x128)
    unsigned short* wt_in = (unsigned short*)(ws + 4 * MB);     // 128KB
    unsigned short* wt_mid = (unsigned short*)(ws + 4 * MB + 128 * KB);   // 512KB
    unsigned short* wt_out = (unsigned short*)(ws + 4 * MB + 640 * KB);   // 512KB
    unsigned short* wt_fc1 = (unsigned short*)(ws + 4 * MB + 1152 * KB);  // 512KB
    unsigned short* qkv1_t = (unsigned short*)(ws + 6 * MB);    // 3MB  (3 x 1024x512)
    unsigned short* qkv2_t = (unsigned short*)(ws + 9 * MB);    // 6MB  (3 x 1024x1024)
    unsigned short* qkv3_t = (unsigned short*)(ws + 15 * MB);   // 3MB  (3 x 512x1024)
    unsigned short* g_b = (unsigned short*)(ws + 18 * MB);      // 8MB  (8192x512)
    unsigned short* t1b = (unsigned short*)(ws + 26 * MB);      // 16MB (8192x1024)
    unsigned short* t2b = (unsigned short*)(ws + 42 * MB);      // 16MB
    unsigned short* h_b = (unsigned short*)(ws + 58 * MB);      // 8MB
    float* xw = (float*)(ws + 66 * MB);                         // 16MB fp32
    float* q = (float*)(ws + 82 * MB);                          // 16MB
    float* kb = (float*)(ws + 98 * MB);                         // 16MB
    float* vb = (float*)(ws + 114 * MB);                        // 16MB (total 130MB)
    float* sc = (float*)t2b;   // 4MB alias, live only after t2b dead
    float* h32 = (float*)t1b;  // 1MB alias, live only after all layers

    // --- weight/activation casts ---
    k_cast<<<NN * F_IN / 1024, 256, 0, stream>>>(x, xb, NN * F_IN);
    dim3 trb(32, 8);
    k_tr<<<dim3(DD / 32, F_IN / 32), trb, 0, stream>>>(w_in, wt_in, F_IN, DD);
    k_tr<<<dim3(DD / 32, DD / 32), trb, 0, stream>>>(w_mid, wt_mid, DD, DD);
    k_tr<<<dim3(DD / 32, DD / 32), trb, 0, stream>>>(w_out, wt_out, DD, DD);
    k_tr<<<dim3(DD / 32, DD / 32), trb, 0, stream>>>(fc1_w, wt_fc1, DD, DD);
    for (int t = 0; t < 3; ++t) {
        k_tr<<<dim3(HH / 32, DD / 32), trb, 0, stream>>>(qkv1_w + (size_t)t * DD * HH,
                                                          qkv1_t + (size_t)t * HH * DD, DD, HH);
        k_tr<<<dim3(HH / 32, HH / 32), trb, 0, stream>>>(qkv2_w + (size_t)t * HH * HH,
                                                          qkv2_t + (size_t)t * HH * HH, HH, HH);
        k_tr<<<dim3(DD / 32, HH / 32), trb, 0, stream>>>(qkv3_w + (size_t)t * HH * DD,
                                                          qkv3_t + (size_t)t * DD * HH, HH, DD);
    }

    // --- degree + CSR build ---
    k_zero_cnt<<<NN / 256, 256, 0, stream>>>(cnt);
    k_count<<<EE / 256, 256, 0, stream>>>(ei, cnt);
    k_dinv<<<NN / 256, 256, 0, stream>>>(cnt, dinv);
    k_scan<<<1, 1024, 0, stream>>>(cnt, off, pos);
    k_fill<<<EE / 256, 256, 0, stream>>>(ei, dinv, pos, csrc, cw);

    auto layer = [&](const unsigned short* hin, const unsigned short* wt,
                     const float* b, int Kin) {
        // GCN: xw = hin @ w (fp32 out), then aggregate (bf16 out)
        gemm_mfma<0, 0><<<dim3(DD / 128, NN / 128), 256, 0, stream>>>(hin, wt, nullptr,
                                                                       xw, Kin, DD);
        gcn_agg<<<NN, 256, 0, stream>>>(xw, b, off, csrc, cw, dinv, g_b);
        // qkv MLPs
        float* dst[3] = {q, kb, vb};
        for (int t = 0; t < 3; ++t) {
            gemm_mfma<1, 1><<<dim3(HH / 128, NN / 128), 256, 0, stream>>>(
                g_b, qkv1_t + (size_t)t * HH * DD, qkv1_b + (size_t)t * HH, t1b, DD, HH);
            gemm_mfma<1, 1><<<dim3(HH / 128, NN / 128), 256, 0, stream>>>(
                t1b, qkv2_t + (size_t)t * HH * HH, qkv2_b + (size_t)t * HH, t2b, HH, HH);
            gemm_mfma<1, 0><<<dim3(DD / 128, NN / 128), 256, 0, stream>>>(
                t2b, qkv3_t + (size_t)t * DD * HH, qkv3_b + (size_t)t * DD, dst[t], HH, DD);
        }
        // cross-document attention (fp32)
        attn_scores<<<dim3(2, 2, NDOC), 256, 0, stream>>>(q, kb, sc);
        softmax128<<<NDOC * 128, 64, 0, stream>>>(sc);
        attn_av<<<dim3(8, 2, NDOC), 256, 0, stream>>>(sc, vb, h_b);
    };

    layer(xb, wt_in, b_in, F_IN);
    layer(h_b, wt_mid, b_mid, DD);
    layer(h_b, wt_mid, b_mid, DD);
    layer(h_b, wt_out, b_out, DD);

    // final FCs + pool + pairwise sigmoid
    gemm_mfma<2, 0><<<dim3(DD / 128, NN / 128), 256, 0, stream>>>(h_b, wt_fc1, fc1_b,
                                                                   xw, DD, DD);
    gemm_nn<2><<<dim3(1, NN / 64), 256, 0, stream>>>(xw, fc2_w, fc2_b, h32, DD, 32);
    pool_fc3<<<NDOC, 128, 0, stream>>>(h32, fc3_w, fc3_b, util);
    final_out<<<1, 64, 0, stream>>>(util, idx_a, idx_b, out);
}

// Round 4
// 1270.266 us; speedup vs baseline: 5.1959x; 1.2112x over previous
//
#include <hip/hip_runtime.h>
#include <math.h>

#define NN 8192
#define NPD 128
#define F_IN 128
#define DD 512
#define HH 1024
#define EE 131072
#define NDOC 64
#define NPAIR 32

typedef __attribute__((ext_vector_type(8))) short bf16x8;
typedef __attribute__((ext_vector_type(4))) float f32x4;
typedef const __attribute__((address_space(1))) void* gas_ptr;
typedef __attribute__((address_space(3))) void* las_ptr;

__device__ __forceinline__ unsigned short f2b(float f) {
    union { float f; unsigned u; } v; v.f = f;
    unsigned r = v.u + 0x7fffu + ((v.u >> 16) & 1u);
    return (unsigned short)(r >> 16);
}
__device__ __forceinline__ float b2f_lo(unsigned u) {
    union { unsigned u; float f; } v; v.u = u << 16; return v.f;
}
__device__ __forceinline__ float b2f_hi(unsigned u) {
    union { unsigned u; float f; } v; v.u = u & 0xffff0000u; return v.f;
}

// ---------------------------------------------------------------------------
// Degree / CSR construction
// ---------------------------------------------------------------------------
__global__ void k_zero_cnt(int* __restrict__ cnt) {
    int i = blockIdx.x * 256 + threadIdx.x;
    if (i < NN) cnt[i] = 0;
}

__global__ void k_count(const int* __restrict__ ei, int* __restrict__ cnt) {
    int e = blockIdx.x * 256 + threadIdx.x;
    if (e < EE) atomicAdd(&cnt[ei[EE + e]], 1);
}

__global__ void k_dinv(const int* __restrict__ cnt, float* __restrict__ dinv) {
    int i = blockIdx.x * 256 + threadIdx.x;
    if (i < NN) dinv[i] = rsqrtf((float)cnt[i] + 1.0f);
}

__global__ void k_scan(const int* __restrict__ cnt, int* __restrict__ off,
                       int* __restrict__ pos) {
    __shared__ int part[1024];
    int t = threadIdx.x;
    int loc[8];
    int s = 0;
    int base = t * 8;
#pragma unroll
    for (int j = 0; j < 8; ++j) { loc[j] = s; s += cnt[base + j]; }
    part[t] = s;
    __syncthreads();
    for (int st = 1; st < 1024; st <<= 1) {
        int v = (t >= st) ? part[t - st] : 0;
        __syncthreads();
        part[t] += v;
        __syncthreads();
    }
    int pre = (t > 0) ? part[t - 1] : 0;
#pragma unroll
    for (int j = 0; j < 8; ++j) {
        int val = pre + loc[j];
        off[base + j] = val;
        pos[base + j] = val;
    }
    if (t == 1023) off[NN] = part[1023];
}

__global__ void k_fill(const int* __restrict__ ei, const float* __restrict__ dinv,
                       int* __restrict__ pos, int* __restrict__ csr_src,
                       float* __restrict__ csr_w) {
    int e = blockIdx.x * 256 + threadIdx.x;
    if (e >= EE) return;
    int r = ei[e];
    int c = ei[EE + e];
    int p = atomicAdd(&pos[c], 1);
    csr_src[p] = r;
    csr_w[p] = dinv[r] * dinv[c];
}

// ---------------------------------------------------------------------------
__global__ void k_cast(const float* __restrict__ in, unsigned short* __restrict__ out,
                       int n) {
    int i = (blockIdx.x * 256 + threadIdx.x) * 4;
    if (i < n) {
        float4 v = *(const float4*)(in + i);
        out[i + 0] = f2b(v.x);
        out[i + 1] = f2b(v.y);
        out[i + 2] = f2b(v.z);
        out[i + 3] = f2b(v.w);
    }
}

// transpose W (K x M fp32) -> Wt (M x K bf16). grid (M/32, K/32), block (32,8)
__global__ void k_tr(const float* __restrict__ in, unsigned short* __restrict__ out,
                     int K, int M) {
    __shared__ float t[32][33];
    int bx = blockIdx.x * 32;
    int by = blockIdx.y * 32;
    int tx = threadIdx.x, ty = threadIdx.y;
    for (int i = ty; i < 32; i += 8)
        t[i][tx] = in[(size_t)(by + i) * M + bx + tx];
    __syncthreads();
    for (int i = ty; i < 32; i += 8)
        out[(size_t)(bx + i) * K + by + tx] = f2b(t[tx][i]);
}

// ---------------------------------------------------------------------------
// bf16 MFMA GEMM (generalized): C = act(A @ Bt^T + bias)
// A: rows x K (lda), Bt: M x K (ldbt), per-z strides; 128x128 tile, BK=64.
// ACT: 0 none, 1 relu, 2 tanh, 3 scale(1/sqrt(512))
// OMODE: 0 fp32 out, 1 bf16 out, 2 bf16 transposed-per-128-row-doc out
// xorb: B z-index = z ^ xorb (cross-doc attention pairing)
// ---------------------------------------------------------------------------
template <int ACT, int OMODE>
__global__ __launch_bounds__(256) void gemm_mfma(
    const unsigned short* __restrict__ A, const unsigned short* __restrict__ Bt,
    const float* __restrict__ bias, void* __restrict__ Cout,
    int K, int lda, int ldbt, int ldc, int mreal,
    long saz, long sbz, long scz, int sbiasz, int xorb) {
    __shared__ unsigned short As[128 * 64];
    __shared__ unsigned short Bs[128 * 64];
    const int z = blockIdx.z;
    A += (size_t)z * saz;
    Bt += (size_t)(z ^ xorb) * sbz;
    if (bias) bias += (size_t)z * sbiasz;

    const int tid = threadIdx.x;
    const int wave = tid >> 6, lane = tid & 63;
    const int m0 = blockIdx.y * 128;
    const int n0 = blockIdx.x * 128;
    const int wm = (wave & 1) * 64, wn = (wave >> 1) * 64;
    const int lhi = lane >> 4;
    const int llo = lane & 15;
    f32x4 acc[4][4] = {};

    const int srow = lane >> 3;
    const int scol = (lane & 7) * 8;
    const unsigned short* ag = A + (size_t)(m0 + wave * 32 + srow) * lda + scol;
    const unsigned short* bg = Bt + (size_t)(n0 + wave * 32 + srow) * ldbt + scol;
    unsigned short* al = As + wave * 2048;
    unsigned short* bl = Bs + wave * 2048;

    for (int k0 = 0; k0 < K; k0 += 64) {
#pragma unroll
        for (int r = 0; r < 4; ++r) {
            __builtin_amdgcn_global_load_lds((gas_ptr)(ag + k0 + (size_t)r * 8 * lda),
                                             (las_ptr)(al + r * 512), 16, 0, 0);
            __builtin_amdgcn_global_load_lds((gas_ptr)(bg + k0 + (size_t)r * 8 * ldbt),
                                             (las_ptr)(bl + r * 512), 16, 0, 0);
        }
        __syncthreads();
#pragma unroll
        for (int s = 0; s < 2; ++s) {
            bf16x8 af[4], bf[4];
#pragma unroll
            for (int i = 0; i < 4; ++i) {
                af[i] = *(const bf16x8*)(As + (wm + i * 16 + llo) * 64 + s * 32 + lhi * 8);
                bf[i] = *(const bf16x8*)(Bs + (wn + i * 16 + llo) * 64 + s * 32 + lhi * 8);
            }
#pragma unroll
            for (int i = 0; i < 4; ++i)
#pragma unroll
                for (int j = 0; j < 4; ++j)
                    acc[i][j] = __builtin_amdgcn_mfma_f32_16x16x32_bf16(af[i], bf[j],
                                                                        acc[i][j], 0, 0, 0);
        }
        __syncthreads();
    }

    float* Cf = (float*)Cout + (size_t)z * scz;
    unsigned short* Cb = (unsigned short*)Cout + (size_t)z * scz;
#pragma unroll
    for (int j = 0; j < 4; ++j) {
        const int col = n0 + wn + j * 16 + llo;
        if (col < mreal) {
            const float bv = bias ? bias[col] : 0.f;
#pragma unroll
            for (int i = 0; i < 4; ++i) {
                const int row = m0 + wm + i * 16 + lhi * 4;
                const int rloc = wm + i * 16 + lhi * 4;
#pragma unroll
                for (int r = 0; r < 4; ++r) {
                    float v = acc[i][j][r] + bv;
                    if (ACT == 1) v = fmaxf(v, 0.f);
                    if (ACT == 2) v = tanhf(v);
                    if (ACT == 3) v *= 0.044194173824159216f;
                    if (OMODE == 0)
                        Cf[(size_t)(row + r) * ldc + col] = v;
                    else if (OMODE == 1)
                        Cb[(size_t)(row + r) * ldc + col] = f2b(v);
                    else
                        Cb[(size_t)blockIdx.y * 65536 + (size_t)col * 128 + rloc + r] = f2b(v);
                }
            }
        }
    }
}

// ---------------------------------------------------------------------------
// GCN aggregation (bf16 in/out): out[i] = tanh(sum w_e*xw[src] + dinv^2*xw[i] + b)
// one block per node; thread t handles dims 2t, 2t+1 (packed uint loads)
// ---------------------------------------------------------------------------
__global__ __launch_bounds__(256) void gcn_agg(const unsigned short* __restrict__ xwb,
                                               const float* __restrict__ bias,
                                               const int* __restrict__ off,
                                               const int* __restrict__ src,
                                               const float* __restrict__ wgt,
                                               const float* __restrict__ dinv,
                                               unsigned short* __restrict__ out) {
    const int node = blockIdx.x;
    const int t = threadIdx.x;
    const int d0 = 2 * t;
    const int beg = off[node], end = off[node + 1];
    float a0 = 0.f, a1 = 0.f;
    for (int e = beg; e < end; ++e) {
        const int s = src[e];
        const float w = wgt[e];
        const unsigned u = *(const unsigned*)(xwb + (size_t)s * DD + d0);
        a0 += w * b2f_lo(u);
        a1 += w * b2f_hi(u);
    }
    const float ns = dinv[node] * dinv[node];
    const unsigned un = *(const unsigned*)(xwb + (size_t)node * DD + d0);
    const float r0 = tanhf(a0 + ns * b2f_lo(un) + bias[d0]);
    const float r1 = tanhf(a1 + ns * b2f_hi(un) + bias[d0 + 1]);
    unsigned o = (unsigned)f2b(r0) | ((unsigned)f2b(r1) << 16);
    *(unsigned*)(out + (size_t)node * DD + d0) = o;
}

// ---------------------------------------------------------------------------
// softmax over rows of 128 (fp32 in, bf16 out); one wave per row
// ---------------------------------------------------------------------------
__global__ __launch_bounds__(64) void softmax128(const float* __restrict__ sc,
                                                 unsigned short* __restrict__ p) {
    const int row = blockIdx.x;
    const float* ip = sc + (size_t)row * 128;
    unsigned short* op = p + (size_t)row * 128;
    const int l = threadIdx.x;
    float a = ip[l], b = ip[l + 64];
    float m = fmaxf(a, b);
#pragma unroll
    for (int s = 32; s; s >>= 1) m = fmaxf(m, __shfl_xor(m, s));
    float e0 = expf(a - m), e1 = expf(b - m);
    float sum = e0 + e1;
#pragma unroll
    for (int s = 32; s; s >>= 1) sum += __shfl_xor(sum, s);
    float inv = 1.f / sum;
    op[l] = f2b(e0 * inv);
    op[l + 64] = f2b(e1 * inv);
}

// ---------------------------------------------------------------------------
__global__ __launch_bounds__(128) void pool_fc3(const float* __restrict__ h32,
                                                const float* __restrict__ w3,
                                                const float* __restrict__ b3,
                                                float* __restrict__ util) {
    const int doc = blockIdx.x;
    const int t = threadIdx.x;
    const float* hp = h32 + (size_t)(doc * 128 + t) * 32;
    float s = 0.f;
#pragma unroll
    for (int j = 0; j < 32; ++j) s += hp[j] * w3[j];
    s += b3[0];
    __shared__ float red[128];
    red[t] = s;
    __syncthreads();
    for (int k = 64; k > 0; k >>= 1) {
        if (t < k) red[t] += red[t + k];
        __syncthreads();
    }
    if (t == 0) util[doc] = red[0] * (1.0f / 128.0f);
}

__global__ void final_out(const float* __restrict__ util, const int* __restrict__ ia,
                          const int* __restrict__ ib, float* __restrict__ out) {
    int i = threadIdx.x;
    if (i < NPAIR) {
        float z = util[ib[i]] - util[ia[i]];
        out[i] = 1.f / (1.f + expf(-z));
    }
}

// ---------------------------------------------------------------------------
extern "C" void kernel_launch(void* const* d_in, const int* in_sizes, int n_in,
                              void* d_out, int out_size, void* d_ws, size_t ws_size,
                              hipStream_t stream) {
    const float* x = (const float*)d_in[0];
    const float* w_in = (const float*)d_in[1];
    const float* b_in = (const float*)d_in[2];
    const float* w_mid = (const float*)d_in[3];
    const float* b_mid = (const float*)d_in[4];
    const float* w_out = (const float*)d_in[5];
    const float* b_out = (const float*)d_in[6];
    const float* fc1_w = (const float*)d_in[7];
    const float* fc1_b = (const float*)d_in[8];
    const float* fc2_w = (const float*)d_in[9];
    const float* fc2_b = (const float*)d_in[10];
    const float* fc3_w = (const float*)d_in[11];
    const float* fc3_b = (const float*)d_in[12];
    const float* qkv1_w = (const float*)d_in[13];
    const float* qkv1_b = (const float*)d_in[14];
    const float* qkv2_w = (const float*)d_in[15];
    const float* qkv2_b = (const float*)d_in[16];
    const float* qkv3_w = (const float*)d_in[17];
    const float* qkv3_b = (const float*)d_in[18];
    const int* ei = (const int*)d_in[19];
    const int* idx_a = (const int*)d_in[22];
    const int* idx_b = (const int*)d_in[23];
    float* out = (float*)d_out;

    char* ws = (char*)d_ws;
    const size_t MB = 1024 * 1024;
    const size_t KB = 1024;
    float* dinv = (float*)(ws + 0);
    int* cnt = (int*)(ws + 64 * KB);
    int* off = (int*)(ws + 128 * KB);
    int* pos = (int*)(ws + 192 * KB);
    int* csrc = (int*)(ws + 256 * KB);
    float* cw = (float*)(ws + 768 * KB);
    float* util = (float*)(ws + 1280 * KB);
    unsigned short* xb = (unsigned short*)(ws + 2 * MB);   // 2MB (8192x128)
    float* h32 = (float*)(ws + 2 * MB);                    // alias, live after layers
    unsigned short* wt_in = (unsigned short*)(ws + 4 * MB);                // 128KB
    unsigned short* wt_mid = (unsigned short*)(ws + 4 * MB + 128 * KB);    // 512KB
    unsigned short* wt_out = (unsigned short*)(ws + 4 * MB + 640 * KB);    // 512KB
    unsigned short* wt_fc1 = (unsigned short*)(ws + 4 * MB + 1152 * KB);   // 512KB
    unsigned short* wt_fc2p = (unsigned short*)(ws + 4 * MB + 1664 * KB);  // 128KB padded
    unsigned short* qkv1_t = (unsigned short*)(ws + 6 * MB);   // 3MB (3072x512)
    unsigned short* qkv2_t = (unsigned short*)(ws + 9 * MB);   // 6MB (3x1024x1024)
    unsigned short* qkv3_t = (unsigned short*)(ws + 15 * MB);  // 3MB (3x512x1024)
    unsigned short* h_b = (unsigned short*)(ws + 18 * MB);     // 8MB
    // Region R1 (48MB @26): t1_all; after qkv2: sc/pbf/qb/kbb/vt alias it
    unsigned short* t1_all = (unsigned short*)(ws + 26 * MB);  // 48MB (8192x3072)
    float* sc = (float*)(ws + 26 * MB);                        // 4MB
    unsigned short* pbf = (unsigned short*)(ws + 30 * MB);     // 2MB
    unsigned short* qb = (unsigned short*)(ws + 32 * MB);      // 8MB
    unsigned short* kbb = (unsigned short*)(ws + 40 * MB);     // 8MB
    unsigned short* vt = (unsigned short*)(ws + 48 * MB);      // 8MB (ends 56)
    // Region R2 (48MB @74): xwb+g_b during GCN; t2_all during qkv; xb2 at end
    unsigned short* xwb = (unsigned short*)(ws + 74 * MB);     // 8MB
    unsigned short* g_b = (unsigned short*)(ws + 82 * MB);     // 8MB
    unsigned short* t2_all = (unsigned short*)(ws + 74 * MB);  // 48MB (ends 122)
    unsigned short* xb2 = (unsigned short*)(ws + 74 * MB);     // 8MB

    // --- weight/activation prep ---
    k_cast<<<NN * F_IN / 1024, 256, 0, stream>>>(x, xb, NN * F_IN);
    hipMemsetAsync(wt_fc2p, 0, 128 * 512 * sizeof(unsigned short), stream);
    dim3 trb(32, 8);
    k_tr<<<dim3(DD / 32, F_IN / 32), trb, 0, stream>>>(w_in, wt_in, F_IN, DD);
    k_tr<<<dim3(DD / 32, DD / 32), trb, 0, stream>>>(w_mid, wt_mid, DD, DD);
    k_tr<<<dim3(DD / 32, DD / 32), trb, 0, stream>>>(w_out, wt_out, DD, DD);
    k_tr<<<dim3(DD / 32, DD / 32), trb, 0, stream>>>(fc1_w, wt_fc1, DD, DD);
    k_tr<<<dim3(1, DD / 32), trb, 0, stream>>>(fc2_w, wt_fc2p, DD, 32);
    for (int t = 0; t < 3; ++t) {
        k_tr<<<dim3(HH / 32, DD / 32), trb, 0, stream>>>(qkv1_w + (size_t)t * DD * HH,
                                                          qkv1_t + (size_t)t * HH * DD, DD, HH);
        k_tr<<<dim3(HH / 32, HH / 32), trb, 0, stream>>>(qkv2_w + (size_t)t * HH * HH,
                                                          qkv2_t + (size_t)t * HH * HH, HH, HH);
        k_tr<<<dim3(DD / 32, HH / 32), trb, 0, stream>>>(qkv3_w + (size_t)t * HH * DD,
                                                          qkv3_t + (size_t)t * DD * HH, HH, DD);
    }

    // --- degree + CSR build ---
    k_zero_cnt<<<NN / 256, 256, 0, stream>>>(cnt);
    k_count<<<EE / 256, 256, 0, stream>>>(ei, cnt);
    k_dinv<<<NN / 256, 256, 0, stream>>>(cnt, dinv);
    k_scan<<<1, 1024, 0, stream>>>(cnt, off, pos);
    k_fill<<<EE / 256, 256, 0, stream>>>(ei, dinv, pos, csrc, cw);

    auto layer = [&](const unsigned short* hin, const unsigned short* wt,
                     const float* b, int Kin) {
        // GCN: xwb = hin @ w (bf16), aggregate -> g_b (bf16)
        gemm_mfma<0, 1><<<dim3(4, 64), 256, 0, stream>>>(
            hin, wt, nullptr, xwb, Kin, Kin, Kin, 512, 512, 0, 0, 0, 0, 0);
        gcn_agg<<<NN, 256, 0, stream>>>(xwb, b, off, csrc, cw, dinv, g_b);
        // qkv1 (wide M=3072), qkv2 (z=3), qkv3 q/k (z=2), qkv3 v (transposed)
        gemm_mfma<1, 1><<<dim3(24, 64), 256, 0, stream>>>(
            g_b, qkv1_t, qkv1_b, t1_all, 512, 512, 512, 3072, 3072, 0, 0, 0, 0, 0);
        gemm_mfma<1, 1><<<dim3(8, 64, 3), 256, 0, stream>>>(
            t1_all, qkv2_t, qkv2_b, t2_all, 1024, 3072, 1024, 3072, 1024,
            1024, 1048576, 1024, 1024, 0);
        gemm_mfma<1, 1><<<dim3(4, 64, 2), 256, 0, stream>>>(
            t2_all, qkv3_t, qkv3_b, qb, 1024, 3072, 1024, 512, 512,
            1024, 524288, 4194304, 512, 0);
        gemm_mfma<1, 2><<<dim3(4, 64), 256, 0, stream>>>(
            t2_all + 2048, qkv3_t + 2 * 524288, qkv3_b + 1024, vt, 1024, 3072, 1024,
            0, 512, 0, 0, 0, 0, 0);
        // attention: scores (bf16 MFMA, cross-doc via xorb), softmax, AV
        gemm_mfma<3, 0><<<dim3(1, 1, NDOC), 256, 0, stream>>>(
            qb, kbb, nullptr, sc, 512, 512, 512, 128, 128,
            65536, 65536, 16384, 0, 1);
        softmax128<<<NDOC * 128, 64, 0, stream>>>(sc, pbf);
        gemm_mfma<0, 1><<<dim3(4, 1, NDOC), 256, 0, stream>>>(
            pbf, vt, nullptr, h_b, 128, 128, 128, 512, 512,
            16384, 65536, 65536, 0, 1);
    };

    layer(xb, wt_in, b_in, F_IN);
    layer(h_b, wt_mid, b_mid, DD);
    layer(h_b, wt_mid, b_mid, DD);
    layer(h_b, wt_out, b_out, DD);

    // final FCs + pool + pairwise sigmoid
    gemm_mfma<2, 1><<<dim3(4, 64), 256, 0, stream>>>(
        h_b, wt_fc1, fc1_b, xb2, 512, 512, 512, 512, 512, 0, 0, 0, 0, 0);
    gemm_mfma<2, 0><<<dim3(1, 64), 256, 0, stream>>>(
        xb2, wt_fc2p, fc2_b, h32, 512, 512, 512, 32, 32, 0, 0, 0, 0, 0);
    pool_fc3<<<NDOC, 128, 0, stream>>>(h32, fc3_w, fc3_b, util);
    final_out<<<1, 64, 0, stream>>>(util, idx_a, idx_b, out);
}